// Round 4
// baseline (610.215 us; speedup 1.0000x reference)
//
#include <hip/hip_runtime.h>
#include <math.h>

// PEER: product-key expert retrieval.
// T=1024 tokens, D=1024, H=8, P=2, NKEYS=256, DKEY=512, TOPK=16.
// Score path REPLICATES the numpy fp32 reference bit-for-bit:
//   q  = xn @ wq^T : OpenBLAS sgemm = sequential-k fp32 FMA chain.
//   sim = einsum   : numpy SSE sum_of_products = 4-lane fp32 partials,
//                    separate mul+add, reduced as (p0+p2)+(p1+p3).
//   combined scores: single fp32 adds.
// Selection noise vs np ref should then be ZERO. Value path fp64-accum.

#define DIMV 1024

// ---------------- K1: rmsnorm: fp64 norm, fp32 elementwise x/n*32 ----------
__global__ __launch_bounds__(256) void peer_rmsnorm(const float* __restrict__ x,
                                                    const float* __restrict__ gamma,
                                                    float* __restrict__ xnf)
{
    int t = blockIdx.x;
    int tid = threadIdx.x;
    const float4* xr = (const float4*)(x + (size_t)t * DIMV);
    float4 v = xr[tid];
    double ss = (double)v.x*v.x + (double)v.y*v.y + (double)v.z*v.z + (double)v.w*v.w;
    #pragma unroll
    for (int off = 32; off > 0; off >>= 1) ss += __shfl_xor(ss, off);
    __shared__ double red[4];
    if ((tid & 63) == 0) red[tid >> 6] = ss;
    __syncthreads();
    double tot = red[0] + red[1] + red[2] + red[3];
    float n32 = (float)fmax(sqrt(tot), 1e-12);
    const float4* g4 = (const float4*)gamma;
    float4 gv = g4[tid];
    float4 o;
    o.x = __fmul_rn(__fmul_rn(__fdiv_rn(v.x, n32), gv.x), 32.0f);
    o.y = __fmul_rn(__fmul_rn(__fdiv_rn(v.y, n32), gv.y), 32.0f);
    o.z = __fmul_rn(__fmul_rn(__fdiv_rn(v.z, n32), gv.z), 32.0f);
    o.w = __fmul_rn(__fmul_rn(__fdiv_rn(v.w, n32), gv.w), 32.0f);
    ((float4*)(xnf + (size_t)t * DIMV))[tid] = o;
}

// ------- K2: q = xn @ wq^T, fp32, sequential-k FMA chain (BLAS mimic) ------
// A: [1024 x 1024] row-major. B: [8192 x 1024] row-major (wq). C: [1024 x 8192].
__global__ __launch_bounds__(256) void peer_qgemm(const float* __restrict__ A,
                                                  const float* __restrict__ Bm,
                                                  float* __restrict__ C)
{
    int m0 = blockIdx.y * 128, n0 = blockIdx.x * 128;
    __shared__ float As[8][128];
    __shared__ float Bs[8][128];
    int tid = threadIdx.x;
    int tx = tid & 15, ty = tid >> 4;
    float acc[8][8] = {};
    int lrow = tid >> 1;           // 0..127
    int lk   = (tid & 1) * 4;      // 0 or 4
    for (int k0 = 0; k0 < 1024; k0 += 8) {
        float4 av = *(const float4*)(A + (long)(m0 + lrow) * 1024 + (k0 + lk));
        As[lk+0][lrow] = av.x; As[lk+1][lrow] = av.y;
        As[lk+2][lrow] = av.z; As[lk+3][lrow] = av.w;
        float4 bv = *(const float4*)(Bm + (long)(n0 + lrow) * 1024 + (k0 + lk));
        Bs[lk+0][lrow] = bv.x; Bs[lk+1][lrow] = bv.y;
        Bs[lk+2][lrow] = bv.z; Bs[lk+3][lrow] = bv.w;
        __syncthreads();
        #pragma unroll
        for (int kk = 0; kk < 8; kk++) {
            float4 a0 = *(const float4*)&As[kk][ty*8];
            float4 a1 = *(const float4*)&As[kk][ty*8+4];
            float4 b0 = *(const float4*)&Bs[kk][tx*8];
            float4 b1 = *(const float4*)&Bs[kk][tx*8+4];
            float ra[8] = {a0.x,a0.y,a0.z,a0.w,a1.x,a1.y,a1.z,a1.w};
            float rb[8] = {b0.x,b0.y,b0.z,b0.w,b1.x,b1.y,b1.z,b1.w};
            #pragma unroll
            for (int i = 0; i < 8; i++)
                #pragma unroll
                for (int j = 0; j < 8; j++)
                    acc[i][j] = __fmaf_rn(ra[i], rb[j], acc[i][j]);
        }
        __syncthreads();
    }
    #pragma unroll
    for (int i = 0; i < 8; i++) {
        float4 c0 = {acc[i][0], acc[i][1], acc[i][2], acc[i][3]};
        float4 c1 = {acc[i][4], acc[i][5], acc[i][6], acc[i][7]};
        *(float4*)(C + (long)(m0 + ty*8 + i) * 8192 + (n0 + tx*8)) = c0;
        *(float4*)(C + (long)(m0 + ty*8 + i) * 8192 + (n0 + tx*8 + 4)) = c1;
    }
}

// ------- K3: sim via numpy-einsum SSE pattern: 4-lane mul/add partials -----
// Block: 8 tokens x 256 keys for one z=(p*8+h). sim col = p*2048 + h*256 + k.
__global__ __launch_bounds__(256) void peer_sim(const float* __restrict__ qf,
                                                const float* __restrict__ keys,
                                                float* __restrict__ simf)
{
    int tb = blockIdx.x;      // 0..127 (token tile of 8)
    int z  = blockIdx.y;      // 0..15
    int h = z & 7, p = z >> 3;
    int tid = threadIdx.x;
    __shared__ float4 qs[8][128];
    int t0 = tb * 8;
    long qbase = (long)h * 512 + (long)p * 4096;
    int row = tid >> 5, c16 = (tid & 31) * 4;
    const float4* qrow = (const float4*)(qf + (long)(t0 + row) * 8192 + qbase);
    #pragma unroll
    for (int u = 0; u < 4; u++) qs[row][c16 + u] = qrow[c16 + u];
    __syncthreads();
    int k = tid;
    const float4* krow = (const float4*)(keys + (long)h * 262144 + (long)k * 1024 + (long)p * 512);
    float pa[8][4] = {};
    for (int d4 = 0; d4 < 128; d4++) {
        float4 kv = krow[d4];
        #pragma unroll
        for (int tt = 0; tt < 8; tt++) {
            float4 qv = qs[tt][d4];
            pa[tt][0] = __fadd_rn(pa[tt][0], __fmul_rn(qv.x, kv.x));
            pa[tt][1] = __fadd_rn(pa[tt][1], __fmul_rn(qv.y, kv.y));
            pa[tt][2] = __fadd_rn(pa[tt][2], __fmul_rn(qv.z, kv.z));
            pa[tt][3] = __fadd_rn(pa[tt][3], __fmul_rn(qv.w, kv.w));
        }
    }
    #pragma unroll
    for (int tt = 0; tt < 8; tt++) {
        float s = __fadd_rn(__fadd_rn(pa[tt][0], pa[tt][2]),
                            __fadd_rn(pa[tt][1], pa[tt][3]));
        simf[(long)(t0 + tt) * 4096 + (long)p * 2048 + h * 256 + k] = s;
    }
}

// ---------------- K4: two-stage top-16 on fp32 sims (one wave/(t,h)) -------
// Replicates jax.lax.top_k tie semantics: value desc, lower index first.
__device__ inline void peer_select16(float v[4], int lane, float* outv, int* outi)
{
    for (int iter = 0; iter < 16; iter++) {
        float bv = -INFINITY; int bk = 1 << 30;
        #pragma unroll
        for (int i = 0; i < 4; i++) {
            int k = i * 64 + lane;
            if (v[i] > bv || (v[i] == bv && k < bk)) { bv = v[i]; bk = k; }
        }
        #pragma unroll
        for (int off = 32; off > 0; off >>= 1) {
            float ov = __shfl_xor(bv, off);
            int   ok = __shfl_xor(bk, off);
            if (ov > bv || (ov == bv && ok < bk)) { bv = ov; bk = ok; }
        }
        if (lane == 0) { outv[iter] = bv; outi[iter] = bk; }
        __syncthreads();
        if ((bk & 63) == lane) v[bk >> 6] = -INFINITY;
    }
}

__global__ __launch_bounds__(64) void peer_topk(const float* __restrict__ sim,
                                                float* __restrict__ wsel,
                                                int* __restrict__ esel)
{
    int b = blockIdx.x;           // b = t*8 + h
    int t = b >> 3, h = b & 7;
    int lane = threadIdx.x;
    const float* simx = sim + (size_t)t * 4096 + h * 256;   // p=0
    const float* simy = simx + 2048;                        // p=1
    __shared__ float sxv[16]; __shared__ int sxi[16];
    __shared__ float syv[16]; __shared__ int syi[16];
    __shared__ float cv[16];  __shared__ int cf[16];
    float v[4];
    #pragma unroll
    for (int i = 0; i < 4; i++) v[i] = simx[i*64 + lane];
    peer_select16(v, lane, sxv, sxi);
    __syncthreads();
    #pragma unroll
    for (int i = 0; i < 4; i++) v[i] = simy[i*64 + lane];
    peer_select16(v, lane, syv, syi);
    __syncthreads();
    // combined 256 fp32 sums, flat f = i*16+j (matches all_scores reshape)
    #pragma unroll
    for (int i = 0; i < 4; i++) {
        int f = i*64 + lane;
        v[i] = __fadd_rn(sxv[f >> 4], syv[f & 15]);
    }
    peer_select16(v, lane, cv, cf);
    __syncthreads();
    double m = (double)cv[0];
    double w = (lane < 16) ? exp((double)cv[lane] - m) : 0.0;
    double Z = w;
    #pragma unroll
    for (int off = 32; off > 0; off >>= 1) Z += __shfl_xor(Z, off);
    if (lane < 16) {
        int f = cf[lane];
        esel[b * 16 + lane] = sxi[f >> 4] * 256 + syi[f & 15];
        wsel[b * 16 + lane] = (float)(w / Z);
    }
}

// ---------------- K5a: gather table_down rows, h = gelu(xn.wd)*w -----------
__global__ __launch_bounds__(256) void peer_down(const float* __restrict__ xn,
                                                 const float* __restrict__ table_down,
                                                 const int* __restrict__ esel,
                                                 const float* __restrict__ wsel,
                                                 float* __restrict__ g)
{
    int tid = threadIdx.x;
    int wv = (blockIdx.x << 2) | (tid >> 6);   // 0..131071 = (t,h,k)
    int lane = tid & 63;
    int t = wv >> 7;
    __shared__ float4 xs[256];
    xs[tid] = ((const float4*)(xn + (size_t)t * DIMV))[tid];
    __syncthreads();
    int e = esel[wv];
    const float4* dr = (const float4*)(table_down + (size_t)e * DIMV);
    double acc = 0.0;
    #pragma unroll
    for (int it = 0; it < 4; it++) {
        int d4 = it * 64 + lane;
        float4 a = xs[d4];
        float4 bb = dr[d4];
        acc = fma((double)a.x, (double)bb.x, acc);
        acc = fma((double)a.y, (double)bb.y, acc);
        acc = fma((double)a.z, (double)bb.z, acc);
        acc = fma((double)a.w, (double)bb.w, acc);
    }
    #pragma unroll
    for (int off = 32; off > 0; off >>= 1) acc += __shfl_xor(acc, off);
    if (lane == 0) {
        double hv = acc;
        double ge = 0.5 * hv * (1.0 + erf(hv * 0.70710678118654752));
        g[wv] = (float)(ge * (double)wsel[wv]);
    }
}

// ---------------- K5b: out[t,:] = sum_j g_j * table_up[e_j,:] --------------
__global__ __launch_bounds__(256) void peer_up(const float* __restrict__ table_up,
                                               const int* __restrict__ esel,
                                               const float* __restrict__ gbuf,
                                               float* __restrict__ out)
{
    int t = blockIdx.x;
    int tid = threadIdx.x;
    __shared__ float gs[128];
    __shared__ int   es[128];
    if (tid < 128) { gs[tid] = gbuf[t * 128 + tid]; es[tid] = esel[t * 128 + tid]; }
    __syncthreads();
    double a0 = 0, a1 = 0, a2 = 0, a3 = 0;
    for (int j = 0; j < 128; j++) {
        const float4* up = (const float4*)(table_up + (size_t)es[j] * DIMV);
        double gj = (double)gs[j];
        float4 u = up[tid];
        a0 = fma(gj, (double)u.x, a0); a1 = fma(gj, (double)u.y, a1);
        a2 = fma(gj, (double)u.z, a2); a3 = fma(gj, (double)u.w, a3);
    }
    float4 o = {(float)a0, (float)a1, (float)a2, (float)a3};
    ((float4*)(out + (size_t)t * DIMV))[tid] = o;
}

extern "C" void kernel_launch(void* const* d_in, const int* in_sizes, int n_in,
                              void* d_out, int out_size, void* d_ws, size_t ws_size,
                              hipStream_t stream)
{
    const float* x          = (const float*)d_in[0];
    const float* gamma      = (const float*)d_in[1];
    const float* wq         = (const float*)d_in[2];
    const float* keys       = (const float*)d_in[3];
    const float* table_down = (const float*)d_in[4];
    const float* table_up   = (const float*)d_in[5];
    float* out = (float*)d_out;
    char* wsb  = (char*)d_ws;

    // workspace layout (bytes)
    float* xnf  = (float*)(wsb);                        //  4 MB [1024 x 1024]
    float* qf   = (float*)(wsb + (4ull<<20));           // 32 MB [1024 x 8192]
    float* simf = (float*)(wsb + (36ull<<20));          // 16 MB [1024 x 4096]
    float* wsel = (float*)(wsb + (52ull<<20));          // 512 KB
    int*   esel = (int*)  (wsb + (52ull<<20) + (512ull<<10));
    float* g    = (float*)(wsb + (53ull<<20));
    if (ws_size < (54ull << 20)) return;  // need 54 MB scratch

    // 1) rmsnorm (fp64 norm -> fp32 scale, mimics np fp32 elementwise)
    peer_rmsnorm<<<1024, 256, 0, stream>>>(x, gamma, xnf);

    // 2) q[t,r] = sum_D xn[t,D]*wq[r,D], fp32 sequential-FMA (BLAS mimic)
    peer_qgemm<<<dim3(64, 8, 1), 256, 0, stream>>>(xnf, wq, qf);

    // 3) sim[t, p*2048+h*256+k] via einsum-SSE 4-lane fp32 partials
    peer_sim<<<dim3(128, 16, 1), 256, 0, stream>>>(qf, keys, simf);

    // 4) two-stage top-16 + softmax weights + expert ids
    peer_topk<<<8192, 64, 0, stream>>>(simf, wsel, esel);

    // 5) h = gelu(xn . table_down[e]) * w   (fp64 accum)
    peer_down<<<32768, 256, 0, stream>>>(xnf, table_down, esel, wsel, g);

    // 6) out = sum g * table_up[e]          (fp64 accum)
    peer_up<<<1024, 256, 0, stream>>>(table_up, esel, g, out);
}

// Round 5
// 608.896 us; speedup vs baseline: 1.0022x; 1.0022x over previous
//
#include <hip/hip_runtime.h>
#include <math.h>

// PEER: product-key expert retrieval.
// Score path replicates numpy fp32 reference bit-for-bit (sequential-k FMA
// chain for q-GEMM; SSE 4-lane mul/add partials for einsum; fp32 adds for
// combined scores). Selection then matches np exactly. Value path fp64-accum
// (order-free, 10x under threshold). This round: scheduling-only optims.

#define DIMV 1024

// ---------------- K1: rmsnorm: fp64 norm, fp32 elementwise x/n*32 ----------
__global__ __launch_bounds__(256) void peer_rmsnorm(const float* __restrict__ x,
                                                    const float* __restrict__ gamma,
                                                    float* __restrict__ xnf)
{
    int t = blockIdx.x;
    int tid = threadIdx.x;
    const float4* xr = (const float4*)(x + (size_t)t * DIMV);
    float4 v = xr[tid];
    double ss = (double)v.x*v.x + (double)v.y*v.y + (double)v.z*v.z + (double)v.w*v.w;
    #pragma unroll
    for (int off = 32; off > 0; off >>= 1) ss += __shfl_xor(ss, off);
    __shared__ double red[4];
    if ((tid & 63) == 0) red[tid >> 6] = ss;
    __syncthreads();
    double tot = red[0] + red[1] + red[2] + red[3];
    float n32 = (float)fmax(sqrt(tot), 1e-12);
    const float4* g4 = (const float4*)gamma;
    float4 gv = g4[tid];
    float4 o;
    o.x = __fmul_rn(__fmul_rn(__fdiv_rn(v.x, n32), gv.x), 32.0f);
    o.y = __fmul_rn(__fmul_rn(__fdiv_rn(v.y, n32), gv.y), 32.0f);
    o.z = __fmul_rn(__fmul_rn(__fdiv_rn(v.z, n32), gv.z), 32.0f);
    o.w = __fmul_rn(__fmul_rn(__fdiv_rn(v.w, n32), gv.w), 32.0f);
    ((float4*)(xnf + (size_t)t * DIMV))[tid] = o;
}

// ------- K2: q = xn @ wq^T, fp32 sequential-k FMA chain (BLAS mimic) -------
// 64x128 tile, K-step 8, double-buffered LDS, 5-stride padded frags.
// A: [1024 x 1024] row-major. B(wq): [8192 x 1024] row-major. C: [1024 x 8192].
// LDS col map: raw col c -> 5*(c>>2) + (c&3)  (4-float frag padded to 5).
__global__ __launch_bounds__(256) void peer_qgemm(const float* __restrict__ A,
                                                  const float* __restrict__ Bm,
                                                  float* __restrict__ C)
{
    __shared__ float As[2][8][80];    // 64 cols -> 16 frags * 5
    __shared__ float Bs[2][8][160];   // 128 cols -> 32 frags * 5
    int tid = threadIdx.x;
    int m0 = blockIdx.y * 64, n0 = blockIdx.x * 128;
    int tx = tid & 15, ty = tid >> 4;          // out: rows ty*4+i, cols tx*8+j
    int rb = tid >> 1, hb = (tid & 1) * 4;     // B loader: row rb, k-half hb
    int ra = rb & 63;                          // A loader (t<128): row ra
    int ca = 5 * (ra >> 2) + (ra & 3);
    int cb = 5 * (rb >> 2) + (rb & 3);
    float acc[4][8] = {};
    // prologue: tile 0
    float4 av, bv;
    if (tid < 128) av = *(const float4*)(A  + (long)(m0 + ra) * 1024 + hb);
    bv = *(const float4*)(Bm + (long)(n0 + rb) * 1024 + hb);
    if (tid < 128) {
        #pragma unroll
        for (int j = 0; j < 4; j++) As[0][hb + j][ca] = ((const float*)&av)[j];
    }
    #pragma unroll
    for (int j = 0; j < 4; j++) Bs[0][hb + j][cb] = ((const float*)&bv)[j];
    int cur = 0;
    for (int k0 = 0; k0 < 1024; k0 += 8) {
        __syncthreads();                       // LDS[cur] ready
        bool more = (k0 + 8) < 1024;
        if (more) {                            // hide global latency under compute
            if (tid < 128) av = *(const float4*)(A  + (long)(m0 + ra) * 1024 + (k0 + 8 + hb));
            bv = *(const float4*)(Bm + (long)(n0 + rb) * 1024 + (k0 + 8 + hb));
        }
        #pragma unroll
        for (int kk = 0; kk < 8; kk++) {
            float4 a0 = *(const float4*)&As[cur][kk][5 * ty];
            float4 b0 = *(const float4*)&Bs[cur][kk][10 * tx];
            float4 b1 = *(const float4*)&Bs[cur][kk][10 * tx + 5];
            float ra4[4] = {a0.x, a0.y, a0.z, a0.w};
            float rb8[8] = {b0.x, b0.y, b0.z, b0.w, b1.x, b1.y, b1.z, b1.w};
            #pragma unroll
            for (int i = 0; i < 4; i++)
                #pragma unroll
                for (int j = 0; j < 8; j++)
                    acc[i][j] = __fmaf_rn(ra4[i], rb8[j], acc[i][j]);
        }
        __syncthreads();                       // all reads of cur done
        if (more) {
            int nxt = cur ^ 1;
            if (tid < 128) {
                #pragma unroll
                for (int j = 0; j < 4; j++) As[nxt][hb + j][ca] = ((const float*)&av)[j];
            }
            #pragma unroll
            for (int j = 0; j < 4; j++) Bs[nxt][hb + j][cb] = ((const float*)&bv)[j];
            cur = nxt;
        }
    }
    #pragma unroll
    for (int i = 0; i < 4; i++) {
        float4 c0 = {acc[i][0], acc[i][1], acc[i][2], acc[i][3]};
        float4 c1 = {acc[i][4], acc[i][5], acc[i][6], acc[i][7]};
        long r = (long)(m0 + ty * 4 + i) * 8192 + (n0 + tx * 8);
        *(float4*)(C + r)     = c0;
        *(float4*)(C + r + 4) = c1;
    }
}

// ------- K3: sim via numpy-einsum SSE pattern: 4-lane mul/add partials -----
// Block: 16 tokens x 256 keys for one z=(p*8+h). sim col = p*2048 + h*256 + k.
__global__ __launch_bounds__(256) void peer_sim(const float* __restrict__ qf,
                                                const float* __restrict__ keys,
                                                float* __restrict__ simf)
{
    int tb = blockIdx.x;      // 0..63 (token tile of 16)
    int z  = blockIdx.y;      // 0..15
    int h = z & 7, p = z >> 3;
    int tid = threadIdx.x;
    __shared__ float4 qs[16][128];
    int t0 = tb * 16;
    long qbase = (long)h * 512 + (long)p * 4096;
    int row = tid >> 4, c0 = (tid & 15) * 8;
    const float4* qrow = (const float4*)(qf + (long)(t0 + row) * 8192 + qbase);
    #pragma unroll
    for (int u = 0; u < 8; u++) qs[row][c0 + u] = qrow[c0 + u];
    __syncthreads();
    int k = tid;
    const float4* krow = (const float4*)(keys + (long)h * 262144 + (long)k * 1024 + (long)p * 512);
    float pa[16][4] = {};
    for (int d4 = 0; d4 < 128; d4++) {
        float4 kv = krow[d4];
        #pragma unroll
        for (int tt = 0; tt < 16; tt++) {
            float4 qv = qs[tt][d4];
            pa[tt][0] = __fadd_rn(pa[tt][0], __fmul_rn(qv.x, kv.x));
            pa[tt][1] = __fadd_rn(pa[tt][1], __fmul_rn(qv.y, kv.y));
            pa[tt][2] = __fadd_rn(pa[tt][2], __fmul_rn(qv.z, kv.z));
            pa[tt][3] = __fadd_rn(pa[tt][3], __fmul_rn(qv.w, kv.w));
        }
    }
    #pragma unroll
    for (int tt = 0; tt < 16; tt++) {
        float s = __fadd_rn(__fadd_rn(pa[tt][0], pa[tt][2]),
                            __fadd_rn(pa[tt][1], pa[tt][3]));
        simf[(long)(t0 + tt) * 4096 + (long)p * 2048 + h * 256 + k] = s;
    }
}

// ---------------- K4: two-stage top-16 on fp32 sims (one wave/(t,h)) -------
// Replicates jax.lax.top_k tie semantics: value desc, lower index first.
__device__ inline void peer_select16(float v[4], int lane, float* outv, int* outi)
{
    for (int iter = 0; iter < 16; iter++) {
        float bv = -INFINITY; int bk = 1 << 30;
        #pragma unroll
        for (int i = 0; i < 4; i++) {
            int k = i * 64 + lane;
            if (v[i] > bv || (v[i] == bv && k < bk)) { bv = v[i]; bk = k; }
        }
        #pragma unroll
        for (int off = 32; off > 0; off >>= 1) {
            float ov = __shfl_xor(bv, off);
            int   ok = __shfl_xor(bk, off);
            if (ov > bv || (ov == bv && ok < bk)) { bv = ov; bk = ok; }
        }
        if (lane == 0) { outv[iter] = bv; outi[iter] = bk; }
        __syncthreads();
        if ((bk & 63) == lane) v[bk >> 6] = -INFINITY;
    }
}

__global__ __launch_bounds__(64) void peer_topk(const float* __restrict__ sim,
                                                float* __restrict__ wsel,
                                                int* __restrict__ esel)
{
    int b = blockIdx.x;           // b = t*8 + h
    int t = b >> 3, h = b & 7;
    int lane = threadIdx.x;
    const float* simx = sim + (size_t)t * 4096 + h * 256;   // p=0
    const float* simy = simx + 2048;                        // p=1
    __shared__ float sxv[16]; __shared__ int sxi[16];
    __shared__ float syv[16]; __shared__ int syi[16];
    __shared__ float cv[16];  __shared__ int cf[16];
    float v[4];
    #pragma unroll
    for (int i = 0; i < 4; i++) v[i] = simx[i*64 + lane];
    peer_select16(v, lane, sxv, sxi);
    __syncthreads();
    #pragma unroll
    for (int i = 0; i < 4; i++) v[i] = simy[i*64 + lane];
    peer_select16(v, lane, syv, syi);
    __syncthreads();
    #pragma unroll
    for (int i = 0; i < 4; i++) {
        int f = i*64 + lane;
        v[i] = __fadd_rn(sxv[f >> 4], syv[f & 15]);
    }
    peer_select16(v, lane, cv, cf);
    __syncthreads();
    double m = (double)cv[0];
    double w = (lane < 16) ? exp((double)cv[lane] - m) : 0.0;
    double Z = w;
    #pragma unroll
    for (int off = 32; off > 0; off >>= 1) Z += __shfl_xor(Z, off);
    if (lane < 16) {
        int f = cf[lane];
        esel[b * 16 + lane] = sxi[f >> 4] * 256 + syi[f & 15];
        wsel[b * 16 + lane] = (float)(w / Z);
    }
}

// ---------------- K5a: gather table_down rows, h = gelu(xn.wd)*w -----------
__global__ __launch_bounds__(256) void peer_down(const float* __restrict__ xn,
                                                 const float* __restrict__ table_down,
                                                 const int* __restrict__ esel,
                                                 const float* __restrict__ wsel,
                                                 float* __restrict__ g)
{
    int tid = threadIdx.x;
    int wv = (blockIdx.x << 2) | (tid >> 6);   // 0..131071 = (t,h,k)
    int lane = tid & 63;
    int t = wv >> 7;
    __shared__ float4 xs[256];
    xs[tid] = ((const float4*)(xn + (size_t)t * DIMV))[tid];
    __syncthreads();
    int e = esel[wv];
    const float4* dr = (const float4*)(table_down + (size_t)e * DIMV);
    double acc = 0.0;
    #pragma unroll
    for (int it = 0; it < 4; it++) {
        int d4 = it * 64 + lane;
        float4 a = xs[d4];
        float4 bb = dr[d4];
        acc = fma((double)a.x, (double)bb.x, acc);
        acc = fma((double)a.y, (double)bb.y, acc);
        acc = fma((double)a.z, (double)bb.z, acc);
        acc = fma((double)a.w, (double)bb.w, acc);
    }
    #pragma unroll
    for (int off = 32; off > 0; off >>= 1) acc += __shfl_xor(acc, off);
    if (lane == 0) {
        double hv = acc;
        double ge = 0.5 * hv * (1.0 + erf(hv * 0.70710678118654752));
        g[wv] = (float)(ge * (double)wsel[wv]);
    }
}

// -------- K5b: out[t, ds*256 .. +255] = sum_j g_j * table_up[e_j, slice] ---
// 4 D-slices per token -> 4096 blocks (16/CU) for latency hiding.
__global__ __launch_bounds__(64) void peer_up(const float* __restrict__ table_up,
                                              const int* __restrict__ esel,
                                              const float* __restrict__ gbuf,
                                              float* __restrict__ out)
{
    int t  = blockIdx.x >> 2;
    int ds = blockIdx.x & 3;
    int lane = threadIdx.x;
    __shared__ float gs[128];
    __shared__ int   es[128];
    gs[lane]      = gbuf[t * 128 + lane];
    gs[lane + 64] = gbuf[t * 128 + 64 + lane];
    es[lane]      = esel[t * 128 + lane];
    es[lane + 64] = esel[t * 128 + 64 + lane];
    __syncthreads();
    int dbase = ds * 256 + lane * 4;
    double a0 = 0, a1 = 0, a2 = 0, a3 = 0;
    for (int j = 0; j < 128; j++) {
        const float4 u = *(const float4*)(table_up + (size_t)es[j] * DIMV + dbase);
        double gj = (double)gs[j];
        a0 = fma(gj, (double)u.x, a0); a1 = fma(gj, (double)u.y, a1);
        a2 = fma(gj, (double)u.z, a2); a3 = fma(gj, (double)u.w, a3);
    }
    float4 o = {(float)a0, (float)a1, (float)a2, (float)a3};
    *(float4*)(out + (size_t)t * DIMV + dbase) = o;
}

extern "C" void kernel_launch(void* const* d_in, const int* in_sizes, int n_in,
                              void* d_out, int out_size, void* d_ws, size_t ws_size,
                              hipStream_t stream)
{
    const float* x          = (const float*)d_in[0];
    const float* gamma      = (const float*)d_in[1];
    const float* wq         = (const float*)d_in[2];
    const float* keys       = (const float*)d_in[3];
    const float* table_down = (const float*)d_in[4];
    const float* table_up   = (const float*)d_in[5];
    float* out = (float*)d_out;
    char* wsb  = (char*)d_ws;

    // workspace layout (bytes)
    float* xnf  = (float*)(wsb);                        //  4 MB [1024 x 1024]
    float* qf   = (float*)(wsb + (4ull<<20));           // 32 MB [1024 x 8192]
    float* simf = (float*)(wsb + (36ull<<20));          // 16 MB [1024 x 4096]
    float* wsel = (float*)(wsb + (52ull<<20));          // 512 KB
    int*   esel = (int*)  (wsb + (52ull<<20) + (512ull<<10));
    float* g    = (float*)(wsb + (53ull<<20));
    if (ws_size < (54ull << 20)) return;  // need 54 MB scratch

    // 1) rmsnorm (fp64 norm -> fp32 scale, mimics np fp32 elementwise)
    peer_rmsnorm<<<1024, 256, 0, stream>>>(x, gamma, xnf);

    // 2) q[t,r] = sum_D xn[t,D]*wq[r,D], fp32 sequential-FMA (BLAS mimic)
    peer_qgemm<<<dim3(64, 16, 1), 256, 0, stream>>>(xnf, wq, qf);

    // 3) sim[t, p*2048+h*256+k] via einsum-SSE 4-lane fp32 partials
    peer_sim<<<dim3(64, 16, 1), 256, 0, stream>>>(qf, keys, simf);

    // 4) two-stage top-16 + softmax weights + expert ids
    peer_topk<<<8192, 64, 0, stream>>>(simf, wsel, esel);

    // 5) h = gelu(xn . table_down[e]) * w   (fp64 accum)
    peer_down<<<32768, 256, 0, stream>>>(xnf, table_down, esel, wsel, g);

    // 6) out = sum g * table_up[e]          (fp64 accum)
    peer_up<<<4096, 64, 0, stream>>>(table_up, esel, g, out);
}

// Round 6
// 557.274 us; speedup vs baseline: 1.0950x; 1.0926x over previous
//
#include <hip/hip_runtime.h>
#include <math.h>

// PEER: product-key expert retrieval.
// Score path replicates numpy fp32 reference bit-for-bit (sequential-k FMA
// chain for q-GEMM; SSE 4-lane mul/add partials for einsum; fp32 adds for
// combined scores). Selection then matches np exactly. Value path fp64-accum.
// R5 post-mortem: padded-stride LDS broke float4 alignment -> scalar ds_read.
// R6: aligned [8][128] tiles, conflict-free frag mapping (tx*4 / tx*4+64),
// register->LDS double buffer, one barrier per K-step.

#define DIMV 1024

// ---------------- K1: rmsnorm: fp64 norm, fp32 elementwise x/n*32 ----------
__global__ __launch_bounds__(256) void peer_rmsnorm(const float* __restrict__ x,
                                                    const float* __restrict__ gamma,
                                                    float* __restrict__ xnf)
{
    int t = blockIdx.x;
    int tid = threadIdx.x;
    const float4* xr = (const float4*)(x + (size_t)t * DIMV);
    float4 v = xr[tid];
    double ss = (double)v.x*v.x + (double)v.y*v.y + (double)v.z*v.z + (double)v.w*v.w;
    #pragma unroll
    for (int off = 32; off > 0; off >>= 1) ss += __shfl_xor(ss, off);
    __shared__ double red[4];
    if ((tid & 63) == 0) red[tid >> 6] = ss;
    __syncthreads();
    double tot = red[0] + red[1] + red[2] + red[3];
    float n32 = (float)fmax(sqrt(tot), 1e-12);
    const float4* g4 = (const float4*)gamma;
    float4 gv = g4[tid];
    float4 o;
    o.x = __fmul_rn(__fmul_rn(__fdiv_rn(v.x, n32), gv.x), 32.0f);
    o.y = __fmul_rn(__fmul_rn(__fdiv_rn(v.y, n32), gv.y), 32.0f);
    o.z = __fmul_rn(__fmul_rn(__fdiv_rn(v.z, n32), gv.z), 32.0f);
    o.w = __fmul_rn(__fmul_rn(__fdiv_rn(v.w, n32), gv.w), 32.0f);
    ((float4*)(xnf + (size_t)t * DIMV))[tid] = o;
}

// ------- K2: q = xn @ wq^T, fp32 sequential-k FMA chain (BLAS mimic) -------
// 128x128 tile, K-step 8, double-buffered aligned LDS [8][128].
// Thread (tx,ty): rows m0+ty*8+i, cols n0+tx*4+j and n0+64+tx*4+j.
// B-frag reads at tx*4 (bank 4tx%32, 2-way = free); A-frag broadcast.
__global__ __launch_bounds__(256) void peer_qgemm(const float* __restrict__ A,
                                                  const float* __restrict__ Bm,
                                                  float* __restrict__ C)
{
    __shared__ float As[2][8][128];
    __shared__ float Bs[2][8][128];
    int tid = threadIdx.x;
    int m0 = blockIdx.y * 128, n0 = blockIdx.x * 128;
    int tx = tid & 15, ty = tid >> 4;
    int lrow = tid >> 1, lk = (tid & 1) * 4;   // loader: row lrow, k-half lk
    float acc[8][8] = {};
    float4 av = *(const float4*)(A  + (long)(m0 + lrow) * 1024 + lk);
    float4 bv = *(const float4*)(Bm + (long)(n0 + lrow) * 1024 + lk);
    #pragma unroll
    for (int j = 0; j < 4; j++) {
        As[0][lk + j][lrow] = ((const float*)&av)[j];
        Bs[0][lk + j][lrow] = ((const float*)&bv)[j];
    }
    __syncthreads();
    int cur = 0;
    for (int k0 = 0; k0 < 1024; k0 += 8) {
        bool more = (k0 + 8) < 1024;
        if (more) {                            // in flight under the 512 FMAs
            av = *(const float4*)(A  + (long)(m0 + lrow) * 1024 + (k0 + 8 + lk));
            bv = *(const float4*)(Bm + (long)(n0 + lrow) * 1024 + (k0 + 8 + lk));
        }
        #pragma unroll
        for (int kk = 0; kk < 8; kk++) {
            float4 a0 = *(const float4*)&As[cur][kk][ty * 8];
            float4 a1 = *(const float4*)&As[cur][kk][ty * 8 + 4];
            float4 b0 = *(const float4*)&Bs[cur][kk][tx * 4];
            float4 b1 = *(const float4*)&Bs[cur][kk][tx * 4 + 64];
            float ra8[8] = {a0.x,a0.y,a0.z,a0.w,a1.x,a1.y,a1.z,a1.w};
            float rb8[8] = {b0.x,b0.y,b0.z,b0.w,b1.x,b1.y,b1.z,b1.w};
            #pragma unroll
            for (int i = 0; i < 8; i++)
                #pragma unroll
                for (int j = 0; j < 8; j++)
                    acc[i][j] = __fmaf_rn(ra8[i], rb8[j], acc[i][j]);
        }
        if (more) {
            int nxt = cur ^ 1;
            #pragma unroll
            for (int j = 0; j < 4; j++) {
                As[nxt][lk + j][lrow] = ((const float*)&av)[j];
                Bs[nxt][lk + j][lrow] = ((const float*)&bv)[j];
            }
            __syncthreads();
            cur = nxt;
        }
    }
    #pragma unroll
    for (int i = 0; i < 8; i++) {
        float4 c0 = {acc[i][0], acc[i][1], acc[i][2], acc[i][3]};
        float4 c1 = {acc[i][4], acc[i][5], acc[i][6], acc[i][7]};
        long r = (long)(m0 + ty * 8 + i) * 8192 + n0;
        *(float4*)(C + r + tx * 4)      = c0;
        *(float4*)(C + r + 64 + tx * 4) = c1;
    }
}

// ------- K3: sim via numpy-einsum SSE pattern: 4-lane mul/add partials -----
// Block: 16 tokens x 256 keys for one z=(p*8+h). sim col = p*2048 + h*256 + k.
__global__ __launch_bounds__(256) void peer_sim(const float* __restrict__ qf,
                                                const float* __restrict__ keys,
                                                float* __restrict__ simf)
{
    int tb = blockIdx.x;      // 0..63 (token tile of 16)
    int z  = blockIdx.y;      // 0..15
    int h = z & 7, p = z >> 3;
    int tid = threadIdx.x;
    __shared__ float4 qs[16][128];
    int t0 = tb * 16;
    long qbase = (long)h * 512 + (long)p * 4096;
    int row = tid >> 4, c0 = (tid & 15) * 8;
    const float4* qrow = (const float4*)(qf + (long)(t0 + row) * 8192 + qbase);
    #pragma unroll
    for (int u = 0; u < 8; u++) qs[row][c0 + u] = qrow[c0 + u];
    __syncthreads();
    int k = tid;
    const float4* krow = (const float4*)(keys + (long)h * 262144 + (long)k * 1024 + (long)p * 512);
    float pa[16][4] = {};
    for (int d4 = 0; d4 < 128; d4++) {
        float4 kv = krow[d4];
        #pragma unroll
        for (int tt = 0; tt < 16; tt++) {
            float4 qv = qs[tt][d4];
            pa[tt][0] = __fadd_rn(pa[tt][0], __fmul_rn(qv.x, kv.x));
            pa[tt][1] = __fadd_rn(pa[tt][1], __fmul_rn(qv.y, kv.y));
            pa[tt][2] = __fadd_rn(pa[tt][2], __fmul_rn(qv.z, kv.z));
            pa[tt][3] = __fadd_rn(pa[tt][3], __fmul_rn(qv.w, kv.w));
        }
    }
    #pragma unroll
    for (int tt = 0; tt < 16; tt++) {
        float s = __fadd_rn(__fadd_rn(pa[tt][0], pa[tt][2]),
                            __fadd_rn(pa[tt][1], pa[tt][3]));
        simf[(long)(t0 + tt) * 4096 + (long)p * 2048 + h * 256 + k] = s;
    }
}

// ---------------- K4: two-stage top-16 on fp32 sims (one wave/(t,h)) -------
// Replicates jax.lax.top_k tie semantics: value desc, lower index first.
__device__ inline void peer_select16(float v[4], int lane, float* outv, int* outi)
{
    for (int iter = 0; iter < 16; iter++) {
        float bv = -INFINITY; int bk = 1 << 30;
        #pragma unroll
        for (int i = 0; i < 4; i++) {
            int k = i * 64 + lane;
            if (v[i] > bv || (v[i] == bv && k < bk)) { bv = v[i]; bk = k; }
        }
        #pragma unroll
        for (int off = 32; off > 0; off >>= 1) {
            float ov = __shfl_xor(bv, off);
            int   ok = __shfl_xor(bk, off);
            if (ov > bv || (ov == bv && ok < bk)) { bv = ov; bk = ok; }
        }
        if (lane == 0) { outv[iter] = bv; outi[iter] = bk; }
        __syncthreads();
        if ((bk & 63) == lane) v[bk >> 6] = -INFINITY;
    }
}

__global__ __launch_bounds__(64) void peer_topk(const float* __restrict__ sim,
                                                float* __restrict__ wsel,
                                                int* __restrict__ esel)
{
    int b = blockIdx.x;           // b = t*8 + h
    int t = b >> 3, h = b & 7;
    int lane = threadIdx.x;
    const float* simx = sim + (size_t)t * 4096 + h * 256;   // p=0
    const float* simy = simx + 2048;                        // p=1
    __shared__ float sxv[16]; __shared__ int sxi[16];
    __shared__ float syv[16]; __shared__ int syi[16];
    __shared__ float cv[16];  __shared__ int cf[16];
    float v[4];
    #pragma unroll
    for (int i = 0; i < 4; i++) v[i] = simx[i*64 + lane];
    peer_select16(v, lane, sxv, sxi);
    __syncthreads();
    #pragma unroll
    for (int i = 0; i < 4; i++) v[i] = simy[i*64 + lane];
    peer_select16(v, lane, syv, syi);
    __syncthreads();
    #pragma unroll
    for (int i = 0; i < 4; i++) {
        int f = i*64 + lane;
        v[i] = __fadd_rn(sxv[f >> 4], syv[f & 15]);
    }
    peer_select16(v, lane, cv, cf);
    __syncthreads();
    double m = (double)cv[0];
    double w = (lane < 16) ? exp((double)cv[lane] - m) : 0.0;
    double Z = w;
    #pragma unroll
    for (int off = 32; off > 0; off >>= 1) Z += __shfl_xor(Z, off);
    if (lane < 16) {
        int f = cf[lane];
        esel[b * 16 + lane] = sxi[f >> 4] * 256 + syi[f & 15];
        wsel[b * 16 + lane] = (float)(w / Z);
    }
}

// ---------------- K5a: gather table_down rows, h = gelu(xn.wd)*w -----------
__global__ __launch_bounds__(256) void peer_down(const float* __restrict__ xn,
                                                 const float* __restrict__ table_down,
                                                 const int* __restrict__ esel,
                                                 const float* __restrict__ wsel,
                                                 float* __restrict__ g)
{
    int tid = threadIdx.x;
    int wv = (blockIdx.x << 2) | (tid >> 6);   // 0..131071 = (t,h,k)
    int lane = tid & 63;
    int t = wv >> 7;
    __shared__ float4 xs[256];
    xs[tid] = ((const float4*)(xn + (size_t)t * DIMV))[tid];
    __syncthreads();
    int e = esel[wv];
    const float4* dr = (const float4*)(table_down + (size_t)e * DIMV);
    double acc = 0.0;
    #pragma unroll
    for (int it = 0; it < 4; it++) {
        int d4 = it * 64 + lane;
        float4 a = xs[d4];
        float4 bb = dr[d4];
        acc = fma((double)a.x, (double)bb.x, acc);
        acc = fma((double)a.y, (double)bb.y, acc);
        acc = fma((double)a.z, (double)bb.z, acc);
        acc = fma((double)a.w, (double)bb.w, acc);
    }
    #pragma unroll
    for (int off = 32; off > 0; off >>= 1) acc += __shfl_xor(acc, off);
    if (lane == 0) {
        double hv = acc;
        double ge = 0.5 * hv * (1.0 + erf(hv * 0.70710678118654752));
        g[wv] = (float)(ge * (double)wsel[wv]);
    }
}

// -------- K5b: out[t, ds*256 .. +255] = sum_j g_j * table_up[e_j, slice] ---
__global__ __launch_bounds__(64) void peer_up(const float* __restrict__ table_up,
                                              const int* __restrict__ esel,
                                              const float* __restrict__ gbuf,
                                              float* __restrict__ out)
{
    int t  = blockIdx.x >> 2;
    int ds = blockIdx.x & 3;
    int lane = threadIdx.x;
    __shared__ float gs[128];
    __shared__ int   es[128];
    gs[lane]      = gbuf[t * 128 + lane];
    gs[lane + 64] = gbuf[t * 128 + 64 + lane];
    es[lane]      = esel[t * 128 + lane];
    es[lane + 64] = esel[t * 128 + 64 + lane];
    __syncthreads();
    int dbase = ds * 256 + lane * 4;
    double a0 = 0, a1 = 0, a2 = 0, a3 = 0;
    for (int j = 0; j < 128; j++) {
        const float4 u = *(const float4*)(table_up + (size_t)es[j] * DIMV + dbase);
        double gj = (double)gs[j];
        a0 = fma(gj, (double)u.x, a0); a1 = fma(gj, (double)u.y, a1);
        a2 = fma(gj, (double)u.z, a2); a3 = fma(gj, (double)u.w, a3);
    }
    float4 o = {(float)a0, (float)a1, (float)a2, (float)a3};
    *(float4*)(out + (size_t)t * DIMV + dbase) = o;
}

extern "C" void kernel_launch(void* const* d_in, const int* in_sizes, int n_in,
                              void* d_out, int out_size, void* d_ws, size_t ws_size,
                              hipStream_t stream)
{
    const float* x          = (const float*)d_in[0];
    const float* gamma      = (const float*)d_in[1];
    const float* wq         = (const float*)d_in[2];
    const float* keys       = (const float*)d_in[3];
    const float* table_down = (const float*)d_in[4];
    const float* table_up   = (const float*)d_in[5];
    float* out = (float*)d_out;
    char* wsb  = (char*)d_ws;

    // workspace layout (bytes)
    float* xnf  = (float*)(wsb);                        //  4 MB [1024 x 1024]
    float* qf   = (float*)(wsb + (4ull<<20));           // 32 MB [1024 x 8192]
    float* simf = (float*)(wsb + (36ull<<20));          // 16 MB [1024 x 4096]
    float* wsel = (float*)(wsb + (52ull<<20));          // 512 KB
    int*   esel = (int*)  (wsb + (52ull<<20) + (512ull<<10));
    float* g    = (float*)(wsb + (53ull<<20));
    if (ws_size < (54ull << 20)) return;  // need 54 MB scratch

    // 1) rmsnorm (fp64 norm -> fp32 scale, mimics np fp32 elementwise)
    peer_rmsnorm<<<1024, 256, 0, stream>>>(x, gamma, xnf);

    // 2) q[t,r] = sum_D xn[t,D]*wq[r,D], fp32 sequential-FMA (BLAS mimic)
    peer_qgemm<<<dim3(64, 8, 1), 256, 0, stream>>>(xnf, wq, qf);

    // 3) sim[t, p*2048+h*256+k] via einsum-SSE 4-lane fp32 partials
    peer_sim<<<dim3(64, 16, 1), 256, 0, stream>>>(qf, keys, simf);

    // 4) two-stage top-16 + softmax weights + expert ids
    peer_topk<<<8192, 64, 0, stream>>>(simf, wsel, esel);

    // 5) h = gelu(xn . table_down[e]) * w   (fp64 accum)
    peer_down<<<32768, 256, 0, stream>>>(xnf, table_down, esel, wsel, g);

    // 6) out = sum g * table_up[e]          (fp64 accum)
    peer_up<<<4096, 64, 0, stream>>>(table_up, esel, g, out);
}

// Round 7
// 542.952 us; speedup vs baseline: 1.1239x; 1.0264x over previous
//
#include <hip/hip_runtime.h>
#include <math.h>

// PEER: product-key expert retrieval.
// Score path replicates numpy fp32 reference bit-for-bit (sequential-k FMA
// chain for q-GEMM; SSE 4-lane mul/add partials for einsum; fp32 adds for
// combined scores). Selection then matches np exactly. Value path fp64-accum.
// R7: qgemm K-step 16 (half the barriers), fused down+up gather kernel
// (one launch, interleaved table streams, 4 blocks/CU).

#define DIMV 1024

// ---------------- K1: rmsnorm: fp64 norm, fp32 elementwise x/n*32 ----------
__global__ __launch_bounds__(256) void peer_rmsnorm(const float* __restrict__ x,
                                                    const float* __restrict__ gamma,
                                                    float* __restrict__ xnf)
{
    int t = blockIdx.x;
    int tid = threadIdx.x;
    const float4* xr = (const float4*)(x + (size_t)t * DIMV);
    float4 v = xr[tid];
    double ss = (double)v.x*v.x + (double)v.y*v.y + (double)v.z*v.z + (double)v.w*v.w;
    #pragma unroll
    for (int off = 32; off > 0; off >>= 1) ss += __shfl_xor(ss, off);
    __shared__ double red[4];
    if ((tid & 63) == 0) red[tid >> 6] = ss;
    __syncthreads();
    double tot = red[0] + red[1] + red[2] + red[3];
    float n32 = (float)fmax(sqrt(tot), 1e-12);
    const float4* g4 = (const float4*)gamma;
    float4 gv = g4[tid];
    float4 o;
    o.x = __fmul_rn(__fmul_rn(__fdiv_rn(v.x, n32), gv.x), 32.0f);
    o.y = __fmul_rn(__fmul_rn(__fdiv_rn(v.y, n32), gv.y), 32.0f);
    o.z = __fmul_rn(__fmul_rn(__fdiv_rn(v.z, n32), gv.z), 32.0f);
    o.w = __fmul_rn(__fmul_rn(__fdiv_rn(v.w, n32), gv.w), 32.0f);
    ((float4*)(xnf + (size_t)t * DIMV))[tid] = o;
}

// ------- K2: q = xn @ wq^T, fp32 sequential-k FMA chain (BLAS mimic) -------
// 128x128 tile, K-step 16, double-buffered aligned LDS [16][128].
// Thread (tx,ty): rows m0+ty*8+i, cols n0+tx*4+j and n0+64+tx*4+j.
__global__ __launch_bounds__(256) void peer_qgemm(const float* __restrict__ A,
                                                  const float* __restrict__ Bm,
                                                  float* __restrict__ C)
{
    __shared__ float As[2][16][128];
    __shared__ float Bs[2][16][128];
    int tid = threadIdx.x;
    int m0 = blockIdx.y * 128, n0 = blockIdx.x * 128;
    int tx = tid & 15, ty = tid >> 4;
    int lrow = tid >> 1, lk8 = (tid & 1) * 8;   // loader: row, k-octet
    float acc[8][8] = {};
    float4 av0 = *(const float4*)(A  + (long)(m0 + lrow) * 1024 + lk8);
    float4 av1 = *(const float4*)(A  + (long)(m0 + lrow) * 1024 + lk8 + 4);
    float4 bv0 = *(const float4*)(Bm + (long)(n0 + lrow) * 1024 + lk8);
    float4 bv1 = *(const float4*)(Bm + (long)(n0 + lrow) * 1024 + lk8 + 4);
    #pragma unroll
    for (int j = 0; j < 4; j++) {
        As[0][lk8 + j][lrow]     = ((const float*)&av0)[j];
        As[0][lk8 + 4 + j][lrow] = ((const float*)&av1)[j];
        Bs[0][lk8 + j][lrow]     = ((const float*)&bv0)[j];
        Bs[0][lk8 + 4 + j][lrow] = ((const float*)&bv1)[j];
    }
    __syncthreads();
    int cur = 0;
    for (int k0 = 0; k0 < 1024; k0 += 16) {
        bool more = (k0 + 16) < 1024;
        if (more) {                            // in flight under 1024 FMAs
            av0 = *(const float4*)(A  + (long)(m0 + lrow) * 1024 + (k0 + 16 + lk8));
            av1 = *(const float4*)(A  + (long)(m0 + lrow) * 1024 + (k0 + 16 + lk8 + 4));
            bv0 = *(const float4*)(Bm + (long)(n0 + lrow) * 1024 + (k0 + 16 + lk8));
            bv1 = *(const float4*)(Bm + (long)(n0 + lrow) * 1024 + (k0 + 16 + lk8 + 4));
        }
        #pragma unroll
        for (int kk = 0; kk < 16; kk++) {
            float4 a0 = *(const float4*)&As[cur][kk][ty * 8];
            float4 a1 = *(const float4*)&As[cur][kk][ty * 8 + 4];
            float4 b0 = *(const float4*)&Bs[cur][kk][tx * 4];
            float4 b1 = *(const float4*)&Bs[cur][kk][tx * 4 + 64];
            float ra8[8] = {a0.x,a0.y,a0.z,a0.w,a1.x,a1.y,a1.z,a1.w};
            float rb8[8] = {b0.x,b0.y,b0.z,b0.w,b1.x,b1.y,b1.z,b1.w};
            #pragma unroll
            for (int i = 0; i < 8; i++)
                #pragma unroll
                for (int j = 0; j < 8; j++)
                    acc[i][j] = __fmaf_rn(ra8[i], rb8[j], acc[i][j]);
        }
        if (more) {
            int nxt = cur ^ 1;
            #pragma unroll
            for (int j = 0; j < 4; j++) {
                As[nxt][lk8 + j][lrow]     = ((const float*)&av0)[j];
                As[nxt][lk8 + 4 + j][lrow] = ((const float*)&av1)[j];
                Bs[nxt][lk8 + j][lrow]     = ((const float*)&bv0)[j];
                Bs[nxt][lk8 + 4 + j][lrow] = ((const float*)&bv1)[j];
            }
            __syncthreads();
            cur = nxt;
        }
    }
    #pragma unroll
    for (int i = 0; i < 8; i++) {
        float4 c0 = {acc[i][0], acc[i][1], acc[i][2], acc[i][3]};
        float4 c1 = {acc[i][4], acc[i][5], acc[i][6], acc[i][7]};
        long r = (long)(m0 + ty * 8 + i) * 8192 + n0;
        *(float4*)(C + r + tx * 4)      = c0;
        *(float4*)(C + r + 64 + tx * 4) = c1;
    }
}

// ------- K3: sim via numpy-einsum SSE pattern: 4-lane mul/add partials -----
__global__ __launch_bounds__(256) void peer_sim(const float* __restrict__ qf,
                                                const float* __restrict__ keys,
                                                float* __restrict__ simf)
{
    int tb = blockIdx.x;      // 0..63 (token tile of 16)
    int z  = blockIdx.y;      // 0..15
    int h = z & 7, p = z >> 3;
    int tid = threadIdx.x;
    __shared__ float4 qs[16][128];
    int t0 = tb * 16;
    long qbase = (long)h * 512 + (long)p * 4096;
    int row = tid >> 4, c0 = (tid & 15) * 8;
    const float4* qrow = (const float4*)(qf + (long)(t0 + row) * 8192 + qbase);
    #pragma unroll
    for (int u = 0; u < 8; u++) qs[row][c0 + u] = qrow[c0 + u];
    __syncthreads();
    int k = tid;
    const float4* krow = (const float4*)(keys + (long)h * 262144 + (long)k * 1024 + (long)p * 512);
    float pa[16][4] = {};
    for (int d4 = 0; d4 < 128; d4++) {
        float4 kv = krow[d4];
        #pragma unroll
        for (int tt = 0; tt < 16; tt++) {
            float4 qv = qs[tt][d4];
            pa[tt][0] = __fadd_rn(pa[tt][0], __fmul_rn(qv.x, kv.x));
            pa[tt][1] = __fadd_rn(pa[tt][1], __fmul_rn(qv.y, kv.y));
            pa[tt][2] = __fadd_rn(pa[tt][2], __fmul_rn(qv.z, kv.z));
            pa[tt][3] = __fadd_rn(pa[tt][3], __fmul_rn(qv.w, kv.w));
        }
    }
    #pragma unroll
    for (int tt = 0; tt < 16; tt++) {
        float s = __fadd_rn(__fadd_rn(pa[tt][0], pa[tt][2]),
                            __fadd_rn(pa[tt][1], pa[tt][3]));
        simf[(long)(t0 + tt) * 4096 + (long)p * 2048 + h * 256 + k] = s;
    }
}

// ---------------- K4: two-stage top-16 on fp32 sims (one wave/(t,h)) -------
__device__ inline void peer_select16(float v[4], int lane, float* outv, int* outi)
{
    for (int iter = 0; iter < 16; iter++) {
        float bv = -INFINITY; int bk = 1 << 30;
        #pragma unroll
        for (int i = 0; i < 4; i++) {
            int k = i * 64 + lane;
            if (v[i] > bv || (v[i] == bv && k < bk)) { bv = v[i]; bk = k; }
        }
        #pragma unroll
        for (int off = 32; off > 0; off >>= 1) {
            float ov = __shfl_xor(bv, off);
            int   ok = __shfl_xor(bk, off);
            if (ov > bv || (ov == bv && ok < bk)) { bv = ov; bk = ok; }
        }
        if (lane == 0) { outv[iter] = bv; outi[iter] = bk; }
        __syncthreads();
        if ((bk & 63) == lane) v[bk >> 6] = -INFINITY;
    }
}

__global__ __launch_bounds__(64) void peer_topk(const float* __restrict__ sim,
                                                float* __restrict__ wsel,
                                                int* __restrict__ esel)
{
    int b = blockIdx.x;           // b = t*8 + h
    int t = b >> 3, h = b & 7;
    int lane = threadIdx.x;
    const float* simx = sim + (size_t)t * 4096 + h * 256;   // p=0
    const float* simy = simx + 2048;                        // p=1
    __shared__ float sxv[16]; __shared__ int sxi[16];
    __shared__ float syv[16]; __shared__ int syi[16];
    __shared__ float cv[16];  __shared__ int cf[16];
    float v[4];
    #pragma unroll
    for (int i = 0; i < 4; i++) v[i] = simx[i*64 + lane];
    peer_select16(v, lane, sxv, sxi);
    __syncthreads();
    #pragma unroll
    for (int i = 0; i < 4; i++) v[i] = simy[i*64 + lane];
    peer_select16(v, lane, syv, syi);
    __syncthreads();
    #pragma unroll
    for (int i = 0; i < 4; i++) {
        int f = i*64 + lane;
        v[i] = __fadd_rn(sxv[f >> 4], syv[f & 15]);
    }
    peer_select16(v, lane, cv, cf);
    __syncthreads();
    double m = (double)cv[0];
    double w = (lane < 16) ? exp((double)cv[lane] - m) : 0.0;
    double Z = w;
    #pragma unroll
    for (int off = 32; off > 0; off >>= 1) Z += __shfl_xor(Z, off);
    if (lane < 16) {
        int f = cf[lane];
        esel[b * 16 + lane] = sxi[f >> 4] * 256 + syi[f & 15];
        wsel[b * 16 + lane] = (float)(w / Z);
    }
}

// ------- K5: fused gather: g = gelu(xn.wd)*w, out = sum g * wu -------------
// One block per token (256 thr). Down: wave w owns experts w*32..w*32+31
// (same per-expert fp64 chain as before). Up: thread owns cols tid*4..+3,
// j-ascending fp64 chain (identical arithmetic to the old peer_up).
__global__ __launch_bounds__(256) void peer_downup(const float* __restrict__ xn,
                                                   const float* __restrict__ table_down,
                                                   const float* __restrict__ table_up,
                                                   const int* __restrict__ esel,
                                                   const float* __restrict__ wsel,
                                                   float* __restrict__ out)
{
    int t = blockIdx.x;
    int tid = threadIdx.x;
    int wid = tid >> 6, lane = tid & 63;
    __shared__ float4 xs[256];
    __shared__ float  gs[128];
    __shared__ int    es[128];
    if (tid < 128) es[tid] = esel[t * 128 + tid];
    xs[tid] = ((const float4*)(xn + (size_t)t * DIMV))[tid];
    __syncthreads();
    // ---- down phase: 2 experts in flight per wave ----
    #pragma unroll 2
    for (int jj = 0; jj < 32; jj++) {
        int j = wid * 32 + jj;
        const float4* dr = (const float4*)(table_down + (size_t)es[j] * DIMV);
        double acc = 0.0;
        #pragma unroll
        for (int it = 0; it < 4; it++) {
            int d4 = it * 64 + lane;
            float4 a = xs[d4];
            float4 bb = dr[d4];
            acc = fma((double)a.x, (double)bb.x, acc);
            acc = fma((double)a.y, (double)bb.y, acc);
            acc = fma((double)a.z, (double)bb.z, acc);
            acc = fma((double)a.w, (double)bb.w, acc);
        }
        #pragma unroll
        for (int off = 32; off > 0; off >>= 1) acc += __shfl_xor(acc, off);
        if (lane == 0) {
            double hv = acc;
            double ge = 0.5 * hv * (1.0 + erf(hv * 0.70710678118654752));
            gs[j] = (float)(ge * (double)wsel[t * 128 + j]);
        }
    }
    __syncthreads();
    // ---- up phase ----
    int dbase = tid * 4;
    double a0 = 0, a1 = 0, a2 = 0, a3 = 0;
    #pragma unroll 4
    for (int j = 0; j < 128; j++) {
        const float4 u = *(const float4*)(table_up + (size_t)es[j] * DIMV + dbase);
        double gj = (double)gs[j];
        a0 = fma(gj, (double)u.x, a0); a1 = fma(gj, (double)u.y, a1);
        a2 = fma(gj, (double)u.z, a2); a3 = fma(gj, (double)u.w, a3);
    }
    float4 o = {(float)a0, (float)a1, (float)a2, (float)a3};
    *(float4*)(out + (size_t)t * DIMV + dbase) = o;
}

extern "C" void kernel_launch(void* const* d_in, const int* in_sizes, int n_in,
                              void* d_out, int out_size, void* d_ws, size_t ws_size,
                              hipStream_t stream)
{
    const float* x          = (const float*)d_in[0];
    const float* gamma      = (const float*)d_in[1];
    const float* wq         = (const float*)d_in[2];
    const float* keys       = (const float*)d_in[3];
    const float* table_down = (const float*)d_in[4];
    const float* table_up   = (const float*)d_in[5];
    float* out = (float*)d_out;
    char* wsb  = (char*)d_ws;

    // workspace layout (bytes)
    float* xnf  = (float*)(wsb);                        //  4 MB [1024 x 1024]
    float* qf   = (float*)(wsb + (4ull<<20));           // 32 MB [1024 x 8192]
    float* simf = (float*)(wsb + (36ull<<20));          // 16 MB [1024 x 4096]
    float* wsel = (float*)(wsb + (52ull<<20));          // 512 KB
    int*   esel = (int*)  (wsb + (52ull<<20) + (512ull<<10));
    if (ws_size < (54ull << 20)) return;  // need 54 MB scratch

    // 1) rmsnorm (fp64 norm -> fp32 scale, mimics np fp32 elementwise)
    peer_rmsnorm<<<1024, 256, 0, stream>>>(x, gamma, xnf);

    // 2) q[t,r] = sum_D xn[t,D]*wq[r,D], fp32 sequential-FMA (BLAS mimic)
    peer_qgemm<<<dim3(64, 8, 1), 256, 0, stream>>>(xnf, wq, qf);

    // 3) sim[t, p*2048+h*256+k] via einsum-SSE 4-lane fp32 partials
    peer_sim<<<dim3(64, 16, 1), 256, 0, stream>>>(qf, keys, simf);

    // 4) two-stage top-16 + softmax weights + expert ids
    peer_topk<<<8192, 64, 0, stream>>>(simf, wsel, esel);

    // 5) fused: g = gelu(xn . wd[e]) * w ; out = sum_j g_j * wu[e_j]
    peer_downup<<<1024, 256, 0, stream>>>(xnf, table_down, table_up,
                                          esel, wsel, out);
}